// Round 1
// baseline (468.346 us; speedup 1.0000x reference)
//
#include <hip/hip_runtime.h>

#define HS 4096       // HIDDEN_SIZE == INPUT_SIZE
#define HS4 (HS / 4)  // 1024 float4 per row

// v2: latency/occupancy fix.
//  - K-split x2: each row's 8 dot products are computed by TWO waves
//    (K-halves of 2048) -> 8192 waves total (2x v1) -> up to 32 waves/CU.
//  - 8-matrix interleaved inner loop: 8 independent dwordx4 weight loads in
//    flight per iteration, 8 independent fp32 accumulator chains.
//  - readfirstlane on wave id -> row/base arithmetic is wave-uniform scalar,
//    weight loads become saddr-form (SGPR base + shared VGPR offset), keeping
//    VGPRs <= 64 so __launch_bounds__(512, 8) (8 waves/SIMD) is honored.
//  - Block = 512 threads = 8 waves = 4 rows; grid = 1024 blocks.
//    LDS = 32 KB (x, h_prev staged) + 256 B partials -> 4 blocks/CU fits.
__global__ __launch_bounds__(512, 8) void lstm_step(
    const float* __restrict__ x,
    const float* __restrict__ hprev,
    const float* __restrict__ cprev,
    const float* __restrict__ Wii, const float* __restrict__ Wif,
    const float* __restrict__ Wig, const float* __restrict__ Wio,
    const float* __restrict__ Whi, const float* __restrict__ Whf,
    const float* __restrict__ Whg, const float* __restrict__ Who,
    const float* __restrict__ bii, const float* __restrict__ bif_,
    const float* __restrict__ big_, const float* __restrict__ bio,
    const float* __restrict__ bhi, const float* __restrict__ bhf,
    const float* __restrict__ bhg, const float* __restrict__ bho,
    float* __restrict__ out, int mode)
{
  __shared__ float4 sx[HS4];   // x: 16 KB
  __shared__ float4 sh[HS4];   // h_prev: 16 KB
  __shared__ float part[8][8]; // [wave][gate-part]: 256 B

  const int tid = threadIdx.x;
  {
    const float4* gx = (const float4*)x;
    const float4* gh = (const float4*)hprev;
    sx[tid] = gx[tid];
    sx[tid + 512] = gx[tid + 512];
    sh[tid] = gh[tid];
    sh[tid + 512] = gh[tid + 512];
  }
  __syncthreads();

  const int lane = tid & 63;
  // wave id is wave-uniform: pin it to an SGPR so all downstream address
  // arithmetic (row, base pointers) is scalar -> saddr loads, low VGPR.
  const int wid = __builtin_amdgcn_readfirstlane(tid >> 6);
  const int rloc = wid >> 1;   // 0..3 : row within block
  const int khalf = wid & 1;   // 0..1 : K-half
  const int row = (blockIdx.x << 2) + rloc;
  const int vbase = khalf << 9;                 // float4 offset of K-half (512)
  const size_t wb = (size_t)row * HS4 + vbase;  // float4 offset into weights

  const float4* __restrict__ W0 = (const float4*)Wii + wb;
  const float4* __restrict__ W1 = (const float4*)Wif + wb;
  const float4* __restrict__ W2 = (const float4*)Wig + wb;
  const float4* __restrict__ W3 = (const float4*)Wio + wb;
  const float4* __restrict__ W4 = (const float4*)Whi + wb;
  const float4* __restrict__ W5 = (const float4*)Whf + wb;
  const float4* __restrict__ W6 = (const float4*)Whg + wb;
  const float4* __restrict__ W7 = (const float4*)Who + wb;

  float a0 = 0.f, a1 = 0.f, a2 = 0.f, a3 = 0.f;
  float a4 = 0.f, a5 = 0.f, a6 = 0.f, a7 = 0.f;

#pragma unroll
  for (int j = 0; j < 8; ++j) {   // 8 iters * 64 lanes * 4 = 2048 elems
    const int idx = (j << 6) + lane;
    const float4 vx = sx[vbase + idx];
    const float4 vh = sh[vbase + idx];
    const float4 w0 = W0[idx];
    const float4 w1 = W1[idx];
    const float4 w2 = W2[idx];
    const float4 w3 = W3[idx];
    const float4 w4 = W4[idx];
    const float4 w5 = W5[idx];
    const float4 w6 = W6[idx];
    const float4 w7 = W7[idx];
    a0 = fmaf(w0.x, vx.x, a0); a0 = fmaf(w0.y, vx.y, a0);
    a0 = fmaf(w0.z, vx.z, a0); a0 = fmaf(w0.w, vx.w, a0);
    a1 = fmaf(w1.x, vx.x, a1); a1 = fmaf(w1.y, vx.y, a1);
    a1 = fmaf(w1.z, vx.z, a1); a1 = fmaf(w1.w, vx.w, a1);
    a2 = fmaf(w2.x, vx.x, a2); a2 = fmaf(w2.y, vx.y, a2);
    a2 = fmaf(w2.z, vx.z, a2); a2 = fmaf(w2.w, vx.w, a2);
    a3 = fmaf(w3.x, vx.x, a3); a3 = fmaf(w3.y, vx.y, a3);
    a3 = fmaf(w3.z, vx.z, a3); a3 = fmaf(w3.w, vx.w, a3);
    a4 = fmaf(w4.x, vh.x, a4); a4 = fmaf(w4.y, vh.y, a4);
    a4 = fmaf(w4.z, vh.z, a4); a4 = fmaf(w4.w, vh.w, a4);
    a5 = fmaf(w5.x, vh.x, a5); a5 = fmaf(w5.y, vh.y, a5);
    a5 = fmaf(w5.z, vh.z, a5); a5 = fmaf(w5.w, vh.w, a5);
    a6 = fmaf(w6.x, vh.x, a6); a6 = fmaf(w6.y, vh.y, a6);
    a6 = fmaf(w6.z, vh.z, a6); a6 = fmaf(w6.w, vh.w, a6);
    a7 = fmaf(w7.x, vh.x, a7); a7 = fmaf(w7.y, vh.y, a7);
    a7 = fmaf(w7.z, vh.z, a7); a7 = fmaf(w7.w, vh.w, a7);
  }

  float acc[8] = {a0, a1, a2, a3, a4, a5, a6, a7};
  // 64-lane butterfly reduction per partial dot
#pragma unroll
  for (int g = 0; g < 8; ++g) {
#pragma unroll
    for (int off = 32; off > 0; off >>= 1)
      acc[g] += __shfl_xor(acc[g], off, 64);
  }

  if (lane == 0) {
#pragma unroll
    for (int g = 0; g < 8; ++g) part[wid][g] = acc[g];
  }
  __syncthreads();

  if (tid < 4) {  // one thread per row combines the two K-halves + gates
    const int r = (blockIdx.x << 2) + tid;
    const int w = tid << 1;
    const float zi = part[w][0] + part[w + 1][0] + part[w][4] + part[w + 1][4]
                     + bii[r] + bhi[r];
    const float zf = part[w][1] + part[w + 1][1] + part[w][5] + part[w + 1][5]
                     + bif_[r] + bhf[r];
    const float zg = part[w][2] + part[w + 1][2] + part[w][6] + part[w + 1][6]
                     + big_[r] + bhg[r];
    const float zo = part[w][3] + part[w + 1][3] + part[w][7] + part[w + 1][7]
                     + bio[r] + bho[r];
    const float it = 1.f / (1.f + __expf(-zi));
    const float ft = 1.f / (1.f + __expf(-zf));
    const float gt = tanhf(zg);
    const float ot = 1.f / (1.f + __expf(-zo));
    const float ct = ft * cprev[r] + it * gt;
    const float ht = ot * tanhf(ct);
    out[r] = ht;
    if (mode >= 3) {
      out[HS + r] = ht;
      out[2 * HS + r] = ct;
    } else if (mode == 2) {
      out[HS + r] = ct;
    }
  }
}

extern "C" void kernel_launch(void* const* d_in, const int* in_sizes, int n_in,
                              void* d_out, int out_size, void* d_ws, size_t ws_size,
                              hipStream_t stream) {
  const float* p[19];
  for (int i = 0; i < 19; ++i) p[i] = (const float*)d_in[i];
  const int mode = out_size / HS;  // 3 expected: [h_t, h_t, c_t]
  lstm_step<<<HS / 4, 512, 0, stream>>>(
      p[0], p[1], p[2],
      p[3], p[4], p[5], p[6],
      p[7], p[8], p[9], p[10],
      p[11], p[12], p[13], p[14],
      p[15], p[16], p[17], p[18],
      (float*)d_out, mode);
}

// Round 2
// 454.146 us; speedup vs baseline: 1.0313x; 1.0313x over previous
//
#include <hip/hip_runtime.h>

#define HS 4096       // HIDDEN_SIZE == INPUT_SIZE
#define HS4 (HS / 4)  // 1024 float4 per row

// v3: deep memory pipeline per wave.
//  - Mapping back to v1: one wave per output row, 4 waves (256 thr) per block,
//    grid = 1024 blocks = exactly 4 blocks/CU resident at 16 waves/CU.
//  - Hand-written 2-stage pipeline: at step j, issue the 8 weight loads +
//    2 LDS reads for step j+1, THEN fma step j's batch. Steady state keeps
//    8-16 dwordx4 wave-loads in flight (8-16 KB/wave) instead of ~1.
//  - __launch_bounds__(256, 4): VGPR cap 128 (pipeline needs ~96), 4 waves/EU.
//  - Gate pairs (W@x and W@h for same gate) are summed BEFORE the butterfly
//    reduction: 4 reductions instead of 8.
__global__ __launch_bounds__(256, 4) void lstm_step(
    const float* __restrict__ x,
    const float* __restrict__ hprev,
    const float* __restrict__ cprev,
    const float* __restrict__ Wii, const float* __restrict__ Wif,
    const float* __restrict__ Wig, const float* __restrict__ Wio,
    const float* __restrict__ Whi, const float* __restrict__ Whf,
    const float* __restrict__ Whg, const float* __restrict__ Who,
    const float* __restrict__ bii, const float* __restrict__ bif_,
    const float* __restrict__ big_, const float* __restrict__ bio,
    const float* __restrict__ bhi, const float* __restrict__ bhf,
    const float* __restrict__ bhg, const float* __restrict__ bho,
    float* __restrict__ out, int mode)
{
  __shared__ float4 sx[HS4];  // x: 16 KB
  __shared__ float4 sh[HS4];  // h_prev: 16 KB
  const int tid = threadIdx.x;
  {
    const float4* gx = (const float4*)x;
    const float4* gh = (const float4*)hprev;
#pragma unroll
    for (int c = 0; c < 4; ++c) {
      sx[tid + 256 * c] = gx[tid + 256 * c];
      sh[tid + 256 * c] = gh[tid + 256 * c];
    }
  }
  __syncthreads();

  const int lane = tid & 63;
  const int wid = __builtin_amdgcn_readfirstlane(tid >> 6);
  const int row = (blockIdx.x << 2) + wid;
  const size_t wb = (size_t)row * HS4;  // float4 offset into each weight mtx

  const float4* __restrict__ W0 = (const float4*)Wii + wb;
  const float4* __restrict__ W1 = (const float4*)Wif + wb;
  const float4* __restrict__ W2 = (const float4*)Wig + wb;
  const float4* __restrict__ W3 = (const float4*)Wio + wb;
  const float4* __restrict__ W4 = (const float4*)Whi + wb;
  const float4* __restrict__ W5 = (const float4*)Whf + wb;
  const float4* __restrict__ W6 = (const float4*)Whg + wb;
  const float4* __restrict__ W7 = (const float4*)Who + wb;

  float a0 = 0.f, a1 = 0.f, a2 = 0.f, a3 = 0.f;
  float a4 = 0.f, a5 = 0.f, a6 = 0.f, a7 = 0.f;

  // ---- pipeline prologue: batch 0 ----
  float4 cw0 = W0[lane], cw1 = W1[lane], cw2 = W2[lane], cw3 = W3[lane];
  float4 cw4 = W4[lane], cw5 = W5[lane], cw6 = W6[lane], cw7 = W7[lane];
  float4 cvx = sx[lane], cvh = sh[lane];

#pragma unroll
  for (int j = 0; j < 16; ++j) {
    const int nidx = ((j + 1) << 6) + lane;
    float4 nw0, nw1, nw2, nw3, nw4, nw5, nw6, nw7, nvx, nvh;
    if (j < 15) {  // compile-time after unroll: prefetch batch j+1
      nvx = sx[nidx];
      nvh = sh[nidx];
      nw0 = W0[nidx];
      nw1 = W1[nidx];
      nw2 = W2[nidx];
      nw3 = W3[nidx];
      nw4 = W4[nidx];
      nw5 = W5[nidx];
      nw6 = W6[nidx];
      nw7 = W7[nidx];
    }
    // fma batch j
    a0 = fmaf(cw0.x, cvx.x, a0); a0 = fmaf(cw0.y, cvx.y, a0);
    a0 = fmaf(cw0.z, cvx.z, a0); a0 = fmaf(cw0.w, cvx.w, a0);
    a1 = fmaf(cw1.x, cvx.x, a1); a1 = fmaf(cw1.y, cvx.y, a1);
    a1 = fmaf(cw1.z, cvx.z, a1); a1 = fmaf(cw1.w, cvx.w, a1);
    a2 = fmaf(cw2.x, cvx.x, a2); a2 = fmaf(cw2.y, cvx.y, a2);
    a2 = fmaf(cw2.z, cvx.z, a2); a2 = fmaf(cw2.w, cvx.w, a2);
    a3 = fmaf(cw3.x, cvx.x, a3); a3 = fmaf(cw3.y, cvx.y, a3);
    a3 = fmaf(cw3.z, cvx.z, a3); a3 = fmaf(cw3.w, cvx.w, a3);
    a4 = fmaf(cw4.x, cvh.x, a4); a4 = fmaf(cw4.y, cvh.y, a4);
    a4 = fmaf(cw4.z, cvh.z, a4); a4 = fmaf(cw4.w, cvh.w, a4);
    a5 = fmaf(cw5.x, cvh.x, a5); a5 = fmaf(cw5.y, cvh.y, a5);
    a5 = fmaf(cw5.z, cvh.z, a5); a5 = fmaf(cw5.w, cvh.w, a5);
    a6 = fmaf(cw6.x, cvh.x, a6); a6 = fmaf(cw6.y, cvh.y, a6);
    a6 = fmaf(cw6.z, cvh.z, a6); a6 = fmaf(cw6.w, cvh.w, a6);
    a7 = fmaf(cw7.x, cvh.x, a7); a7 = fmaf(cw7.y, cvh.y, a7);
    a7 = fmaf(cw7.z, cvh.z, a7); a7 = fmaf(cw7.w, cvh.w, a7);
    if (j < 15) {  // rotate (register renaming after unroll, no copies)
      cw0 = nw0; cw1 = nw1; cw2 = nw2; cw3 = nw3;
      cw4 = nw4; cw5 = nw5; cw6 = nw6; cw7 = nw7;
      cvx = nvx; cvh = nvh;
    }
  }

  // combine x-gate and h-gate partials BEFORE reduction: 4 butterflies not 8
  float acc[4] = {a0 + a4, a1 + a5, a2 + a6, a3 + a7};
#pragma unroll
  for (int g = 0; g < 4; ++g) {
#pragma unroll
    for (int off = 32; off > 0; off >>= 1)
      acc[g] += __shfl_xor(acc[g], off, 64);
  }

  if (lane == 0) {
    const float zi = acc[0] + bii[row] + bhi[row];
    const float zf = acc[1] + bif_[row] + bhf[row];
    const float zg = acc[2] + big_[row] + bhg[row];
    const float zo = acc[3] + bio[row] + bho[row];
    const float it = 1.f / (1.f + __expf(-zi));
    const float ft = 1.f / (1.f + __expf(-zf));
    const float gt = tanhf(zg);
    const float ot = 1.f / (1.f + __expf(-zo));
    const float ct = ft * cprev[row] + it * gt;
    const float ht = ot * tanhf(ct);
    out[row] = ht;
    if (mode >= 3) {
      out[HS + row] = ht;
      out[2 * HS + row] = ct;
    } else if (mode == 2) {
      out[HS + row] = ct;
    }
  }
}

extern "C" void kernel_launch(void* const* d_in, const int* in_sizes, int n_in,
                              void* d_out, int out_size, void* d_ws, size_t ws_size,
                              hipStream_t stream) {
  const float* p[19];
  for (int i = 0; i < 19; ++i) p[i] = (const float*)d_in[i];
  const int mode = out_size / HS;  // 3 expected: [h_t, h_t, c_t]
  lstm_step<<<HS / 4, 256, 0, stream>>>(
      p[0], p[1], p[2],
      p[3], p[4], p[5], p[6],
      p[7], p[8], p[9], p[10],
      p[11], p[12], p[13], p[14],
      p[15], p[16], p[17], p[18],
      (float*)d_out, mode);
}